// Round 6
// baseline (93.012 us; speedup 1.0000x reference)
//
#include <hip/hip_runtime.h>
#include <hip/hip_bf16.h>

// RingConv2d via f16 MFMA implicit GEMM, register-pipelined phases.
// out[b,o,i,j] = sum_{c,kh,kw} cos(xpad - w): cos(a-b)=cos a cos b + sin a sin b
// GEMM: M=o(128), N=px(32*64*64), K=1152 = 4 cgroups x 9 taps x (16c x 2trig)
// MFMA 16x16x32_f16 lane k-map: k = {4g+j (j<4), 16+4g+(j-4)}, g=lane>>4
// Pixel payload 64B reordered in 4 groups of 16B: group g = channels
// {2g,2g+1,8+2g,8+2g+1} x (cos,sin)  ->  B-frag = ONE uint4 at byte g*16.
// LDS pixel stride 80B (16B-aligned b128, uniform bank spread).
// Per kpos phase: prefetch next B(4x b128)+A(4x uint4) into regs, then
// setprio(1) 16-MFMA cluster setprio(0).  (T3-lite + T5)

typedef _Float16 half8 __attribute__((ext_vector_type(8)));
typedef float f32x4 __attribute__((ext_vector_type(4)));

#define NB 32
#define NC 64
#define NH 64
#define NW 64
#define NO 128
#define PW 66
#define PSTRIDE 80   // LDS bytes per pixel

union U16 { unsigned short u; _Float16 h; };
union HB { uint4 u4; half8 h; };

__device__ inline unsigned pack_cs(float ang) {
    float s, c;
    sincosf(ang, &s, &c);
    U16 uc, us; uc.h = (_Float16)c; us.h = (_Float16)s;
    return (unsigned)uc.u | ((unsigned)us.u << 16);   // cos low, sin high
}

__device__ inline unsigned pack_cs_fast(float ang) {
    float s, c;
    __sincosf(ang, &s, &c);
    U16 uc, us; uc.h = (_Float16)c; us.h = (_Float16)s;
    return (unsigned)uc.u | ((unsigned)us.u << 16);
}

// ---- prep x: [b][c][h][w] f32 -> xp[b][cg][1+row][1+col] 64B pixel.
// uint4 group q holds channels {2q,2q+1,8+2q,9+2q} of the 16-ch cgroup.
__global__ __launch_bounds__(256) void prep_x(const float* __restrict__ x,
                                              uint4* __restrict__ xp) {
    __shared__ unsigned ls[64 * 65];
    const int b = blockIdx.x >> 6, row = blockIdx.x & 63;
    const int t = threadIdx.x;
#pragma unroll
    for (int pass = 0; pass < 16; ++pass) {
        int c = pass * 4 + (t >> 6);
        int col = t & 63;
        float v = x[((size_t)(b * NC + c) * NH + row) * NW + col];
        ls[c * 65 + col] = pack_cs_fast(v);
    }
    __syncthreads();
    const int q = t & 3, col = t >> 2;
#pragma unroll
    for (int cg = 0; cg < 4; ++cg) {
        uint4 vv;
        vv.x = ls[(cg * 16 + 2 * q + 0) * 65 + col];
        vv.y = ls[(cg * 16 + 2 * q + 1) * 65 + col];
        vv.z = ls[(cg * 16 + 8 + 2 * q) * 65 + col];
        vv.w = ls[(cg * 16 + 9 + 2 * q) * 65 + col];
        xp[(size_t)(((b * 4 + cg) * PW + row + 1) * PW + col + 1) * 4 + q] = vv;
    }
}

// ---- fill padded border pixels with (cos,sin)=(1,0) for every channel
__global__ __launch_bounds__(256) void prep_border(uint4* __restrict__ xp) {
    const int bc = blockIdx.x;                  // 0..127 = b*4+cg
    uint4* base = xp + (size_t)bc * PW * PW * 4;
    const uint4 v = make_uint4(0x3C00u, 0x3C00u, 0x3C00u, 0x3C00u);
    for (int idx = threadIdx.x; idx < 260 * 4; idx += 256) {
        int p = idx >> 2, q = idx & 3;
        int r, c;
        if (p < 66)       { r = 0;       c = p; }
        else if (p < 132) { r = 65;      c = p - 66; }
        else if (p < 196) { r = p - 131; c = 0; }
        else              { r = p - 195; c = 65; }
        base[(size_t)(r * PW + c) * 4 + q] = v;
    }
}

// ---- prep w: OIHW f32 -> wq[chunk36][o128][g4] 16B = A-fragment order
// (c_sub map {2g,2g+1,8+2g,9+2g} matches the new pixel payload order)
__global__ __launch_bounds__(256) void prep_w(const float* __restrict__ w,
                                              uint4* __restrict__ wq) {
    int t = blockIdx.x * 256 + threadIdx.x;     // 36*128*4 = 18432
    if (t >= 36 * 128 * 4) return;
    int g = t & 3, o = (t >> 2) & 127, chunk = t >> 9;
    int cg = chunk / 9, kpos = chunk % 9, kh = kpos / 3, kw = kpos % 3;
    unsigned r[4];
#pragma unroll
    for (int m = 0; m < 4; ++m) {
        int c_sub = (m < 2) ? (2 * g + m) : (8 + 2 * g + (m - 2));
        int c = cg * 16 + c_sub;
        float ang = w[((o * NC + c) * 3 + kh) * 3 + kw];
        r[m] = pack_cs(ang);
    }
    wq[t] = make_uint4(r[0], r[1], r[2], r[3]);
}

// ---- conv: block = 16x16 px x 64 o, 4 waves; dbuf LDS + reg-pipelined phases
__global__ __launch_bounds__(256, 3) void ring_conv(const uint4* __restrict__ xp,
                                                    const uint4* __restrict__ wq,
                                                    float* __restrict__ out) {
    __shared__ __align__(16) char xs[2][324 * PSTRIDE];   // 2 x 25920 B

    // chunked XCD swizzle (bijective: 1024 = 8*128)
    const int d = blockIdx.x;
    const int blk = (d & 7) * 128 + (d >> 3);

    const int ob = blk & 1;                   // o base 0/64
    const int pxb = blk >> 1;
    const int jt = pxb & 3, itile = (pxb >> 2) & 3, b = pxb >> 4;
    const int row0 = itile * 16, col0 = jt * 16;

    const int t = threadIdx.x, lane = t & 63, wid = t >> 6;
    const int l15 = lane & 15, g = lane >> 4;

    f32x4 acc[4][4] = {};                      // [px-row r][o-frag f]

    // staging geometry: element e = k*256 + t ; pixel p=e>>2, quad q=e&3
    int goff[6], loff[6];
#pragma unroll
    for (int k = 0; k < 6; ++k) {
        int e = k * 256 + t;
        if (e > 1295) e = 1295;               // clamp tail (dup harmless)
        int p = e >> 2, q = e & 3;
        int rr = p / 18, cc = p % 18;
        goff[k] = ((row0 + rr) * PW + (col0 + cc)) * 4 + q;
        loff[k] = p * PSTRIDE + q * 16;
    }
    const bool tail = (t < 16);
    const size_t img_stride = (size_t)PW * PW * 4;
    const uint4* img0 = xp + (size_t)(b * 4) * img_stride;

    // prologue: stage cg0 -> buf0
    {
        uint4 S[6];
#pragma unroll
        for (int k = 0; k < 5; ++k) S[k] = img0[goff[k]];
        if (tail) S[5] = img0[goff[5]];
#pragma unroll
        for (int k = 0; k < 5; ++k) *(uint4*)&xs[0][loff[k]] = S[k];
        if (tail) *(uint4*)&xs[0][loff[5]] = S[5];
    }
    __syncthreads();

    const uint4* wb = wq + (size_t)(ob * 64 + l15) * 4 + g;

    for (int cg = 0; cg < 4; ++cg) {
        const int cur = cg & 1;
        const char* xbuf = xs[cur];
        const uint4* wcg = wb + (size_t)(cg * 9) * 512;

        HB A[2][4], Bv[2][4];
        // preload kpos0 operands
#pragma unroll
        for (int f = 0; f < 4; ++f) A[0][f].u4 = wcg[f * 64];
#pragma unroll
        for (int r = 0; r < 4; ++r)
            Bv[0][r].u4 = *(const uint4*)(xbuf + ((wid * 4 + r) * 18 + l15) * PSTRIDE + g * 16);

        // issue next-cg stage loads (in flight across the whole cg)
        uint4 S[6];
        if (cg < 3) {
            const uint4* img = img0 + (size_t)(cg + 1) * img_stride;
#pragma unroll
            for (int k = 0; k < 5; ++k) S[k] = img[goff[k]];
            if (tail) S[5] = img[goff[5]];
        }

#pragma unroll
        for (int kpos = 0; kpos < 9; ++kpos) {
            const int cp = kpos & 1, np = cp ^ 1;
            if (kpos < 8) {     // prefetch next phase operands into regs
                const int kh1 = (kpos + 1) / 3, kw1 = (kpos + 1) % 3;
#pragma unroll
                for (int r = 0; r < 4; ++r)
                    Bv[np][r].u4 = *(const uint4*)(xbuf
                        + ((wid * 4 + r + kh1) * 18 + l15 + kw1) * PSTRIDE + g * 16);
#pragma unroll
                for (int f = 0; f < 4; ++f) A[np][f].u4 = wcg[(kpos + 1) * 512 + f * 64];
            }
            __builtin_amdgcn_s_setprio(1);
#pragma unroll
            for (int r = 0; r < 4; ++r)
#pragma unroll
                for (int f = 0; f < 4; ++f)
                    acc[r][f] = __builtin_amdgcn_mfma_f32_16x16x32_f16(A[cp][f].h, Bv[cp][r].h,
                                                                       acc[r][f], 0, 0, 0);
            __builtin_amdgcn_s_setprio(0);
        }

        if (cg < 3) {          // write staged regs into the other buffer
            char* dst = xs[cur ^ 1];
#pragma unroll
            for (int k = 0; k < 5; ++k) *(uint4*)&dst[loff[k]] = S[k];
            if (tail) *(uint4*)&dst[loff[5]] = S[5];
        }
        __syncthreads();
    }

    // epilogue: D col = l15 = px col, row = 4g+i = o within frag
#pragma unroll
    for (int r = 0; r < 4; ++r) {
        int orow = row0 + wid * 4 + r;
#pragma unroll
        for (int f = 0; f < 4; ++f) {
            int o0 = ob * 64 + f * 16 + 4 * g;
            float* p = out + (((size_t)b * NO + o0) * NH + orow) * NW + col0 + l15;
#pragma unroll
            for (int i = 0; i < 4; ++i)
                p[(size_t)i * NH * NW] = acc[r][f][i];
        }
    }
}

extern "C" void kernel_launch(void* const* d_in, const int* in_sizes, int n_in,
                              void* d_out, int out_size, void* d_ws, size_t ws_size,
                              hipStream_t stream) {
    const float* x = (const float*)d_in[0];
    const float* w = (const float*)d_in[1];

    uint4* xpnt = (uint4*)d_ws;                                  // 35.7 MB padded
    uint4* wqp = (uint4*)((char*)d_ws + (size_t)36 * 1024 * 1024);

    prep_border<<<NB * 4, 256, 0, stream>>>(xpnt);
    prep_x<<<NB * NH, 256, 0, stream>>>(x, xpnt);
    prep_w<<<72, 256, 0, stream>>>(w, wqp);
    ring_conv<<<1024, 256, 0, stream>>>(xpnt, wqp, (float*)d_out);
}

// Round 7
// 82.167 us; speedup vs baseline: 1.1320x; 1.1320x over previous
//
#include <hip/hip_runtime.h>
#include <hip/hip_bf16.h>

// RingConv2d via f16 MFMA implicit GEMM, wide-N tile (v7).
// out[b,o,i,j] = sum_{c,kh,kw} cos(xpad - w): cos(a-b)=cos a cos b + sin a sin b
// GEMM: M=o(128), N=px(32*64*64), K=1152 = 4 cgroups x 9 taps x (16c x 2trig)
// MFMA 16x16x32_f16; A and B store logical-k in the SAME (g,j) element order,
// so the k-permutation cancels (dot-product is k-order invariant).
// Pixel payload 64B: quad q = channels {2q,2q+1,8+2q,9+2q} x (cos,sin).
// LDS pixel stride 72B (18 words: 18*l15 mod 32 bijective on even banks -> clean).
// Block = 64 o x (32x16) px, 4 waves; per wave 8 px-rows, 32 MFMA per kpos
// against 4 A-loads (reg-ring prefetch depth 2 = ~310 cy L2 cover).

typedef _Float16 half8 __attribute__((ext_vector_type(8)));
typedef float f32x4 __attribute__((ext_vector_type(4)));

#define NB 32
#define NC 64
#define NH 64
#define NW 64
#define NO 128
#define PW 66
#define PSTRIDE 72   // LDS bytes per pixel

union U16 { unsigned short u; _Float16 h; };
union HB { uint4 u4; unsigned long long q[2]; half8 h; };

__device__ inline unsigned pack_cs(float ang) {
    float s, c;
    sincosf(ang, &s, &c);
    U16 uc, us; uc.h = (_Float16)c; us.h = (_Float16)s;
    return (unsigned)uc.u | ((unsigned)us.u << 16);   // cos low, sin high
}

__device__ inline unsigned pack_cs_fast(float ang) {
    float s, c;
    __sincosf(ang, &s, &c);
    U16 uc, us; uc.h = (_Float16)c; us.h = (_Float16)s;
    return (unsigned)uc.u | ((unsigned)us.u << 16);
}

// ---- prep x: [b][c][h][w] f32 -> xp[b][cg][1+row][1+col] 64B pixel.
// uint4 quad q holds channels {2q,2q+1,8+2q,9+2q} of the 16-ch cgroup.
__global__ __launch_bounds__(256) void prep_x(const float* __restrict__ x,
                                              uint4* __restrict__ xp) {
    __shared__ unsigned ls[64 * 65];
    const int b = blockIdx.x >> 6, row = blockIdx.x & 63;
    const int t = threadIdx.x;
#pragma unroll
    for (int pass = 0; pass < 16; ++pass) {
        int c = pass * 4 + (t >> 6);
        int col = t & 63;
        float v = x[((size_t)(b * NC + c) * NH + row) * NW + col];
        ls[c * 65 + col] = pack_cs_fast(v);
    }
    __syncthreads();
    const int q = t & 3, col = t >> 2;
#pragma unroll
    for (int cg = 0; cg < 4; ++cg) {
        uint4 vv;
        vv.x = ls[(cg * 16 + 2 * q + 0) * 65 + col];
        vv.y = ls[(cg * 16 + 2 * q + 1) * 65 + col];
        vv.z = ls[(cg * 16 + 8 + 2 * q) * 65 + col];
        vv.w = ls[(cg * 16 + 9 + 2 * q) * 65 + col];
        xp[(size_t)(((b * 4 + cg) * PW + row + 1) * PW + col + 1) * 4 + q] = vv;
    }
}

// ---- fill padded border pixels with (cos,sin)=(1,0)
__global__ __launch_bounds__(256) void prep_border(uint4* __restrict__ xp) {
    const int bc = blockIdx.x;                  // 0..127 = b*4+cg
    uint4* base = xp + (size_t)bc * PW * PW * 4;
    const uint4 v = make_uint4(0x3C00u, 0x3C00u, 0x3C00u, 0x3C00u);
    for (int idx = threadIdx.x; idx < 260 * 4; idx += 256) {
        int p = idx >> 2, q = idx & 3;
        int r, c;
        if (p < 66)       { r = 0;       c = p; }
        else if (p < 132) { r = 65;      c = p - 66; }
        else if (p < 196) { r = p - 131; c = 0; }
        else              { r = p - 195; c = 65; }
        base[(size_t)(r * PW + c) * 4 + q] = v;
    }
}

// ---- prep w: OIHW f32 -> wq[chunk36][o128][g4] 16B = A-fragment order
// c_sub map {2g,2g+1,8+2g,9+2g} == pixel quad map (consistent k-permutation)
__global__ __launch_bounds__(256) void prep_w(const float* __restrict__ w,
                                              uint4* __restrict__ wq) {
    int t = blockIdx.x * 256 + threadIdx.x;     // 36*128*4 = 18432
    if (t >= 36 * 128 * 4) return;
    int g = t & 3, o = (t >> 2) & 127, chunk = t >> 9;
    int cg = chunk / 9, kpos = chunk % 9, kh = kpos / 3, kw = kpos % 3;
    unsigned r[4];
#pragma unroll
    for (int m = 0; m < 4; ++m) {
        int c_sub = (m < 2) ? (2 * g + m) : (8 + 2 * g + (m - 2));
        int c = cg * 16 + c_sub;
        float ang = w[((o * NC + c) * 3 + kh) * 3 + kw];
        r[m] = pack_cs(ang);
    }
    wq[t] = make_uint4(r[0], r[1], r[2], r[3]);
}

// ---- conv v7: block = 64 o x (32x16) px, 4 waves x 8 px-rows
__global__ __launch_bounds__(256, 2) void ring_conv(const uint4* __restrict__ xp,
                                                    const uint4* __restrict__ wq,
                                                    float* __restrict__ out) {
    __shared__ __align__(16) char xs[34 * 18 * PSTRIDE];   // 44064 B

    // chunked XCD swizzle (bijective: 512 = 8*64)
    const int d = blockIdx.x;
    const int blk = (d & 7) * 64 + (d >> 3);

    const int ob = blk & 1;                   // o base 0/64
    const int pxb = blk >> 1;                 // 256 = 4 jt x 2 it2 x 32 b
    const int jt = pxb & 3, it2 = (pxb >> 2) & 1, b = pxb >> 3;
    const int row0 = it2 * 32, col0 = jt * 16;

    const int t = threadIdx.x, lane = t & 63, wid = t >> 6;
    const int l15 = lane & 15, g = lane >> 4;

    f32x4 acc[8][4] = {};                      // [px-row r][o-frag f]

    const size_t img_stride = (size_t)PW * PW * 4;
    const uint4* img0 = xp + (size_t)(b * 4) * img_stride;
    const uint4* wb = wq + (size_t)(ob * 64 + l15) * 4 + g;

    for (int cg = 0; cg < 4; ++cg) {
        __syncthreads();
        // stage x tile: 34 rows x 18 cols x 4 quads = 2448 uint4
        const uint4* img = img0 + (size_t)cg * img_stride;
#pragma unroll
        for (int k = 0; k < 10; ++k) {
            int e = k * 256 + t;
            if (e > 2447) e = 2447;           // clamp tail (dup write benign)
            int p = e >> 2, q = e & 3;
            int rr = p / 18, cc = p - rr * 18;
            uint4 v = img[((row0 + rr) * PW + (col0 + cc)) * 4 + q];
            char* dst = xs + p * PSTRIDE + q * 16;
            *(unsigned long long*)dst = (unsigned long long)v.x | ((unsigned long long)v.y << 32);
            *(unsigned long long*)(dst + 8) = (unsigned long long)v.z | ((unsigned long long)v.w << 32);
        }
        __syncthreads();

        const uint4* wcg = wb + (size_t)(cg * 9) * 512;
        HB A[2][4];
#pragma unroll
        for (int f = 0; f < 4; ++f) A[0][f].u4 = wcg[0 * 512 + f * 64];
#pragma unroll
        for (int f = 0; f < 4; ++f) A[1][f].u4 = wcg[1 * 512 + f * 64];

#pragma unroll
        for (int kpos = 0; kpos < 9; ++kpos) {
            const int kh = kpos / 3, kw = kpos % 3;
            HB* Ac = A[kpos & 1];
#pragma unroll
            for (int r = 0; r < 8; ++r) {
                int pix = (wid * 8 + r + kh) * 18 + l15 + kw;
                const char* sp = xs + pix * PSTRIDE + g * 16;
                HB Bv;
                Bv.q[0] = *(const unsigned long long*)sp;        // k: ch 2g,2g+1
                Bv.q[1] = *(const unsigned long long*)(sp + 8);  // k: ch 8+2g,9+2g
#pragma unroll
                for (int f = 0; f < 4; ++f)
                    acc[r][f] = __builtin_amdgcn_mfma_f32_16x16x32_f16(Ac[f].h, Bv.h,
                                                                       acc[r][f], 0, 0, 0);
            }
            if (kpos < 7) {   // refill consumed slot with A(kpos+2): ~310cy cover
#pragma unroll
                for (int f = 0; f < 4; ++f) Ac[f].u4 = wcg[(kpos + 2) * 512 + f * 64];
            }
        }
    }

    // epilogue: D col = l15 = px col, row = 4g+i = o within frag
#pragma unroll
    for (int r = 0; r < 8; ++r) {
        int orow = row0 + wid * 8 + r;
#pragma unroll
        for (int f = 0; f < 4; ++f) {
            int o0 = ob * 64 + f * 16 + 4 * g;
            float* p = out + (((size_t)b * NO + o0) * NH + orow) * NW + col0 + l15;
#pragma unroll
            for (int i = 0; i < 4; ++i)
                p[(size_t)i * NH * NW] = acc[r][f][i];
        }
    }
}

extern "C" void kernel_launch(void* const* d_in, const int* in_sizes, int n_in,
                              void* d_out, int out_size, void* d_ws, size_t ws_size,
                              hipStream_t stream) {
    const float* x = (const float*)d_in[0];
    const float* w = (const float*)d_in[1];

    uint4* xpnt = (uint4*)d_ws;                                  // 35.7 MB padded
    uint4* wqp = (uint4*)((char*)d_ws + (size_t)36 * 1024 * 1024);

    prep_border<<<NB * 4, 256, 0, stream>>>(xpnt);
    prep_x<<<NB * NH, 256, 0, stream>>>(x, xpnt);
    prep_w<<<72, 256, 0, stream>>>(w, wqp);
    ring_conv<<<512, 256, 0, stream>>>(xpnt, wqp, (float*)d_out);
}

// Round 8
// 68.067 us; speedup vs baseline: 1.3665x; 1.2071x over previous
//
#include <hip/hip_runtime.h>
#include <hip/hip_bf16.h>

// RingConv2d via f16 MFMA implicit GEMM, 32x32x16 shape (v8).
// out[b,o,i,j] = sum_{c,kh,kw} cos(xpad - w): cos(a-b)=cos a cos b + sin a sin b
// GEMM: M=o(128), N=px(32*64*64), K=1152 = 4cg x 9 taps x 2 kk x (8c x 2trig)
// MFMA 32x32x16_f16: A row=lane&31, B col=lane&31, k-halves by lane>>5 with
// IDENTICAL j-order on A and B (consistent permutation -> k-map cancels).
// C/D (measured m74/m101): col=lane&31, row=(reg&3)+8*(reg>>2)+4*(lane>>5).
// Pixel payload 64B: quad q = channels {4q..4q+3} x (cos,sin); quad = 2*kk+g2.
// LDS pixel stride 72B. Block = 128 o x (4x32) px, 4 waves x 1 o-frag.

typedef _Float16 half8 __attribute__((ext_vector_type(8)));
typedef float f32x16 __attribute__((ext_vector_type(16)));

#define NB 32
#define NC 64
#define NH 64
#define NW 64
#define NO 128
#define PW 66
#define PSTRIDE 72   // LDS bytes per pixel
#define TPX 204      // 6 rows x 34 cols staged pixels

union U16 { unsigned short u; _Float16 h; };
union HB { uint4 u4; unsigned long long q[2]; half8 h; };

__device__ inline unsigned pack_cs(float ang) {
    float s, c;
    sincosf(ang, &s, &c);
    U16 uc, us; uc.h = (_Float16)c; us.h = (_Float16)s;
    return (unsigned)uc.u | ((unsigned)us.u << 16);   // cos low, sin high
}

__device__ inline unsigned pack_cs_fast(float ang) {
    float s, c;
    __sincosf(ang, &s, &c);
    U16 uc, us; uc.h = (_Float16)c; us.h = (_Float16)s;
    return (unsigned)uc.u | ((unsigned)us.u << 16);
}

// ---- prep x: [b][c][h][w] f32 -> xp[b][cg][1+row][1+col] 64B pixel.
// quad q = channels {4q..4q+3} x (cos,sin)
__global__ __launch_bounds__(256) void prep_x(const float* __restrict__ x,
                                              uint4* __restrict__ xp) {
    __shared__ unsigned ls[64 * 65];
    const int b = blockIdx.x >> 6, row = blockIdx.x & 63;
    const int t = threadIdx.x;
#pragma unroll
    for (int pass = 0; pass < 16; ++pass) {
        int c = pass * 4 + (t >> 6);
        int col = t & 63;
        float v = x[((size_t)(b * NC + c) * NH + row) * NW + col];
        ls[c * 65 + col] = pack_cs_fast(v);
    }
    __syncthreads();
    const int q = t & 3, col = t >> 2;
#pragma unroll
    for (int cg = 0; cg < 4; ++cg) {
        uint4 vv;
        vv.x = ls[(cg * 16 + 4 * q + 0) * 65 + col];
        vv.y = ls[(cg * 16 + 4 * q + 1) * 65 + col];
        vv.z = ls[(cg * 16 + 4 * q + 2) * 65 + col];
        vv.w = ls[(cg * 16 + 4 * q + 3) * 65 + col];
        xp[(size_t)(((b * 4 + cg) * PW + row + 1) * PW + col + 1) * 4 + q] = vv;
    }
}

// ---- fill padded border pixels with (cos,sin)=(1,0)
__global__ __launch_bounds__(256) void prep_border(uint4* __restrict__ xp) {
    const int bc = blockIdx.x;                  // 0..127 = b*4+cg
    uint4* base = xp + (size_t)bc * PW * PW * 4;
    const uint4 v = make_uint4(0x3C00u, 0x3C00u, 0x3C00u, 0x3C00u);
    for (int idx = threadIdx.x; idx < 260 * 4; idx += 256) {
        int p = idx >> 2, q = idx & 3;
        int r, c;
        if (p < 66)       { r = 0;       c = p; }
        else if (p < 132) { r = 65;      c = p - 66; }
        else if (p < 196) { r = p - 131; c = 0; }
        else              { r = p - 195; c = 65; }
        base[(size_t)(r * PW + c) * 4 + q] = v;
    }
}

// ---- prep w: OIHW f32 -> wqa[(cg*9+kpos)*2+kk][o128][g2] 16B A-fragments.
// lane 16B = channels {8kk + 4g2 .. +3} x (cos,sin) -- j-order == pixel quads.
__global__ __launch_bounds__(256) void prep_w(const float* __restrict__ w,
                                              uint4* __restrict__ wqa) {
    int t = blockIdx.x * 256 + threadIdx.x;     // 36*2*128*2 = 18432
    if (t >= 36 * 2 * 128 * 2) return;
    int g2 = t & 1, o = (t >> 1) & 127, kk = (t >> 8) & 1, chunk = t >> 9;
    int cg = chunk / 9, kpos = chunk % 9, kh = kpos / 3, kw = kpos % 3;
    unsigned r[4];
#pragma unroll
    for (int m = 0; m < 4; ++m) {
        int c = cg * 16 + kk * 8 + g2 * 4 + m;
        float ang = w[((o * NC + c) * 3 + kh) * 3 + kw];
        r[m] = pack_cs(ang);
    }
    wqa[t] = make_uint4(r[0], r[1], r[2], r[3]);
}

// ---- conv v8: block = 128 o x (4x32) px, 4 waves; 32x32x16 MFMA
__global__ __launch_bounds__(256, 3) void ring_conv(const uint4* __restrict__ xp,
                                                    const uint4* __restrict__ wqa,
                                                    float* __restrict__ out) {
    __shared__ __align__(16) char xs[TPX * PSTRIDE];   // 14688 B

    // chunked XCD swizzle (bijective: 1024 = 8*128)
    const int d = blockIdx.x;
    const int blk = (d & 7) * 128 + (d >> 3);

    // blk: ch = col-half, rq = row-quad, b
    const int ch = blk & 1, rq = (blk >> 1) & 15, b = blk >> 5;
    const int row0 = rq * 4, col0 = ch * 32;

    const int t = threadIdx.x, lane = t & 63, wid = t >> 6;
    const int l31 = lane & 31, g2 = lane >> 5;

    f32x16 acc[4] = {};                        // [px-row r]

    // staging geometry: 204 px x 4 quads = 816 uint4; e = pass*256 + t
    int goff[4], loff[4];
#pragma unroll
    for (int k = 0; k < 4; ++k) {
        int e = k * 256 + t;
        if (e > 815) e = 815;                 // clamp tail (dup write benign)
        int p = e >> 2, q = e & 3;
        int rr = p / 34, cc = p - rr * 34;
        goff[k] = ((row0 + rr) * PW + (col0 + cc)) * 4 + q;
        loff[k] = p * PSTRIDE + q * 16;
    }
    const size_t img_stride = (size_t)PW * PW * 4;
    const uint4* img0 = xp + (size_t)(b * 4) * img_stride;

    // per-lane LDS byte base for B-reads
    const int xlane = l31 * PSTRIDE + g2 * 16;
    // per-lane A offset (uint4 units): o = 32*wid + l31 rows, half g2
    const int aoff = (wid * 32 + l31) * 2 + g2;

    // prologue: stage cg0
    {
        uint4 S[4];
#pragma unroll
        for (int k = 0; k < 4; ++k) S[k] = img0[goff[k]];
#pragma unroll
        for (int k = 0; k < 4; ++k) {
            char* dst = xs + loff[k];
            *(unsigned long long*)dst = (unsigned long long)S[k].x | ((unsigned long long)S[k].y << 32);
            *(unsigned long long*)(dst + 8) = (unsigned long long)S[k].z | ((unsigned long long)S[k].w << 32);
        }
    }
    __syncthreads();

    for (int cg = 0; cg < 4; ++cg) {
        // issue next-cg stage loads (in flight under the whole cg compute)
        uint4 S[4];
        if (cg < 3) {
            const uint4* img = img0 + (size_t)(cg + 1) * img_stride;
#pragma unroll
            for (int k = 0; k < 4; ++k) S[k] = img[goff[k]];
        }

        const uint4* wa = wqa + (size_t)(cg * 9 * 2) * 256 + aoff;

        HB Aop[2], Bop[2][4];
        Aop[0].u4 = wa[0];
        Aop[1].u4 = wa[256];
#pragma unroll
        for (int r = 0; r < 4; ++r) {          // B for s=0 (kpos0,kk0)
            const char* sp = xs + r * 34 * PSTRIDE + xlane;
            Bop[0][r].q[0] = *(const unsigned long long*)sp;
            Bop[0][r].q[1] = *(const unsigned long long*)(sp + 8);
        }

#pragma unroll
        for (int s = 0; s < 18; ++s) {         // s = kpos*2 + kk
            const int cp = s & 1, np = cp ^ 1;
            if (s < 17) {                      // prefetch B(s+1)
                const int s1 = s + 1, kp1 = s1 >> 1, kk1 = s1 & 1;
                const int kh1 = kp1 / 3, kw1 = kp1 % 3;
#pragma unroll
                for (int r = 0; r < 4; ++r) {
                    const char* sp = xs + (((r + kh1) * 34 + kw1) * PSTRIDE + kk1 * 32) + xlane;
                    Bop[np][r].q[0] = *(const unsigned long long*)sp;
                    Bop[np][r].q[1] = *(const unsigned long long*)(sp + 8);
                }
            }
            __builtin_amdgcn_s_setprio(1);
#pragma unroll
            for (int r = 0; r < 4; ++r)
                acc[r] = __builtin_amdgcn_mfma_f32_32x32x16_f16(Aop[cp].h, Bop[cp][r].h,
                                                                acc[r], 0, 0, 0);
            __builtin_amdgcn_s_setprio(0);
            if (s < 16) Aop[cp].u4 = wa[(s + 2) * 256];   // refill A ring (depth 2)
        }

        __syncthreads();                       // all xs reads done
        if (cg < 3) {
#pragma unroll
            for (int k = 0; k < 4; ++k) {
                char* dst = xs + loff[k];
                *(unsigned long long*)dst = (unsigned long long)S[k].x | ((unsigned long long)S[k].y << 32);
                *(unsigned long long*)(dst + 8) = (unsigned long long)S[k].z | ((unsigned long long)S[k].w << 32);
            }
        }
        __syncthreads();                       // xs(cg+1) visible
    }

    // epilogue: C/D col=l31=px col, row = (reg&3)+8*(reg>>2)+4*g2 = o in frag
#pragma unroll
    for (int r = 0; r < 4; ++r) {
        const int orow = row0 + r;
#pragma unroll
        for (int reg = 0; reg < 16; ++reg) {
            int o = wid * 32 + (reg & 3) + 8 * (reg >> 2) + 4 * g2;
            out[(((size_t)b * NO + o) * NH + orow) * NW + col0 + l31] = acc[r][reg];
        }
    }
}

extern "C" void kernel_launch(void* const* d_in, const int* in_sizes, int n_in,
                              void* d_out, int out_size, void* d_ws, size_t ws_size,
                              hipStream_t stream) {
    const float* x = (const float*)d_in[0];
    const float* w = (const float*)d_in[1];

    uint4* xpnt = (uint4*)d_ws;                                  // 35.7 MB padded
    uint4* wqp = (uint4*)((char*)d_ws + (size_t)36 * 1024 * 1024);

    prep_border<<<NB * 4, 256, 0, stream>>>(xpnt);
    prep_x<<<NB * NH, 256, 0, stream>>>(x, xpnt);
    prep_w<<<72, 256, 0, stream>>>(w, wqp);
    ring_conv<<<1024, 256, 0, stream>>>(xpnt, wqp, (float*)d_out);
}

// Round 9
// 57.334 us; speedup vs baseline: 1.6223x; 1.1872x over previous
//
#include <hip/hip_runtime.h>
#include <hip/hip_bf16.h>

// RingConv2d via f16 MFMA implicit GEMM, 32x32x16, wide-M wave (v9).
// GEMM: M=o(128), N=px(32*64*64), K=1152 = 4cg x 9 taps x 2 kk x (8c x 2trig)
// MFMA 32x32x16_f16, consistent A/B k-permutation (k-order cancels in dot).
// C/D (measured): col=lane&31, row=(reg&3)+8*(reg>>2)+4*(lane>>5).
// Wave = 2 o-frags x 4 px-rows = 8 MFMA/step vs 4 LDS B-frags (B reuse x2).
// vmcnt FIFO discipline: A ring (depth 4) + B(0) preloaded BEFORE the S
// stage loads, so A-consumes never drain S (r8 bug fixed).

typedef _Float16 half8 __attribute__((ext_vector_type(8)));
typedef float f32x16 __attribute__((ext_vector_type(16)));

#define NB 32
#define NC 64
#define NH 64
#define NW 64
#define NO 128
#define PW 66
#define PSTRIDE 72    // LDS bytes per pixel
#define TROWS 10
#define TCOLS 34
#define TPX (TROWS * TCOLS)   // 340 staged pixels

union U16 { unsigned short u; _Float16 h; };
union HB { uint4 u4; unsigned long long q[2]; half8 h; };

__device__ inline unsigned pack_cs(float ang) {
    float s, c;
    sincosf(ang, &s, &c);
    U16 uc, us; uc.h = (_Float16)c; us.h = (_Float16)s;
    return (unsigned)uc.u | ((unsigned)us.u << 16);   // cos low, sin high
}

__device__ inline unsigned pack_cs_fast(float ang) {
    float s, c;
    __sincosf(ang, &s, &c);
    U16 uc, us; uc.h = (_Float16)c; us.h = (_Float16)s;
    return (unsigned)uc.u | ((unsigned)us.u << 16);
}

// ---- single prep dispatch: x-pack (2048 blocks) + w-pack (72) + border (128)
__global__ __launch_bounds__(256) void prep_all(const float* __restrict__ x,
                                                const float* __restrict__ w,
                                                uint4* __restrict__ xp,
                                                uint4* __restrict__ wqa) {
    __shared__ unsigned ls[64 * 65];
    const int blk = blockIdx.x;
    const int t = threadIdx.x;

    if (blk < NB * NH) {
        // x: [b][c][h][w] f32 -> xp[b][cg][1+row][1+col] 64B pixel,
        // quad q = channels {4q..4q+3} x (cos,sin)
        const int b = blk >> 6, row = blk & 63;
#pragma unroll
        for (int pass = 0; pass < 16; ++pass) {
            int c = pass * 4 + (t >> 6);
            int col = t & 63;
            float v = x[((size_t)(b * NC + c) * NH + row) * NW + col];
            ls[c * 65 + col] = pack_cs_fast(v);
        }
        __syncthreads();
        const int q = t & 3, col = t >> 2;
#pragma unroll
        for (int cg = 0; cg < 4; ++cg) {
            uint4 vv;
            vv.x = ls[(cg * 16 + 4 * q + 0) * 65 + col];
            vv.y = ls[(cg * 16 + 4 * q + 1) * 65 + col];
            vv.z = ls[(cg * 16 + 4 * q + 2) * 65 + col];
            vv.w = ls[(cg * 16 + 4 * q + 3) * 65 + col];
            xp[(size_t)(((b * 4 + cg) * PW + row + 1) * PW + col + 1) * 4 + q] = vv;
        }
    } else if (blk < NB * NH + 72) {
        // w: OIHW f32 -> wqa[(cg*9+kpos)*2+kk][o128][g2] 16B A-fragments,
        // lane 16B = channels {8kk+4g2 .. +3} x (cos,sin)
        int tt = (blk - NB * NH) * 256 + t;          // 36*2*128*2 = 18432
        if (tt < 36 * 2 * 128 * 2) {
            int g2 = tt & 1, o = (tt >> 1) & 127, kk = (tt >> 8) & 1, chunk = tt >> 9;
            int cg = chunk / 9, kpos = chunk % 9, kh = kpos / 3, kw = kpos % 3;
            unsigned r[4];
#pragma unroll
            for (int m = 0; m < 4; ++m) {
                int c = cg * 16 + kk * 8 + g2 * 4 + m;
                float ang = w[((o * NC + c) * 3 + kh) * 3 + kw];
                r[m] = pack_cs(ang);
            }
            wqa[tt] = make_uint4(r[0], r[1], r[2], r[3]);
        }
    } else {
        // border pixels = (cos,sin)=(1,0)
        const int bc = blk - NB * NH - 72;           // 0..127 = b*4+cg
        uint4* base = xp + (size_t)bc * PW * PW * 4;
        const uint4 v = make_uint4(0x3C00u, 0x3C00u, 0x3C00u, 0x3C00u);
        for (int idx = t; idx < 260 * 4; idx += 256) {
            int p = idx >> 2, q = idx & 3;
            int r, c;
            if (p < 66)       { r = 0;       c = p; }
            else if (p < 132) { r = 65;      c = p - 66; }
            else if (p < 196) { r = p - 131; c = 0; }
            else              { r = p - 195; c = 65; }
            base[(size_t)(r * PW + c) * 4 + q] = v;
        }
    }
}

// ---- conv v9: block = 128 o x (8x32) px, 4 waves x (2 o-frag x 4 rows)
__global__ __launch_bounds__(256, 2) void ring_conv(const uint4* __restrict__ xp,
                                                    const uint4* __restrict__ wqa,
                                                    float* __restrict__ out) {
    __shared__ __align__(16) char xs[TPX * PSTRIDE];   // 24480 B

    // chunked XCD swizzle (bijective: 512 = 8*64)
    const int d = blockIdx.x;
    const int blk = (d & 7) * 64 + (d >> 3);

    const int ch = blk & 1, rq = (blk >> 1) & 7, b = blk >> 4;
    const int row0 = rq * 8, col0 = ch * 32;

    const int t = threadIdx.x, lane = t & 63, wid = t >> 6;
    const int l31 = lane & 31, g2 = lane >> 5;
    const int op = wid & 1, rg = wid >> 1;             // o-pair, row-group
    const int rowbase = rg * 4;

    f32x16 acc[2][4] = {};                             // [o-frag f][px-row r]

    // staging geometry: 340 px x 4 quads = 1360 uint4; 6 passes, last partial
    int goff[6], loff[6];
#pragma unroll
    for (int k = 0; k < 6; ++k) {
        int e = k * 256 + t;
        if (e > TPX * 4 - 1) e = TPX * 4 - 1;          // dup tail benign
        int p = e >> 2, q = e & 3;
        int rr = p / TCOLS, cc = p - rr * TCOLS;
        goff[k] = ((row0 + rr) * PW + (col0 + cc)) * 4 + q;
        loff[k] = p * PSTRIDE + q * 16;
    }
    const size_t img_stride = (size_t)PW * PW * 4;
    const uint4* img0 = xp + (size_t)(b * 4) * img_stride;

    const int xlane = l31 * PSTRIDE + g2 * 16;
    // A: frag f covers o = op*64 + 32f + l31, half g2
    const uint4* wbase = wqa + (op * 64 + l31) * 2 + g2;

    // prologue: stage cg0
    {
        uint4 S[6];
#pragma unroll
        for (int k = 0; k < 6; ++k) S[k] = img0[goff[k]];
#pragma unroll
        for (int k = 0; k < 6; ++k) {
            char* dst = xs + loff[k];
            *(unsigned long long*)dst = (unsigned long long)S[k].x | ((unsigned long long)S[k].y << 32);
            *(unsigned long long*)(dst + 8) = (unsigned long long)S[k].z | ((unsigned long long)S[k].w << 32);
        }
    }
    __syncthreads();

    for (int cg = 0; cg < 4; ++cg) {
        const uint4* wa = wbase + (size_t)(cg * 18) * 256;

        // (1) A ring depth 4 + B(0) preloads -- BEFORE S loads (vmcnt FIFO)
        HB Ar[4][2];
#pragma unroll
        for (int i = 0; i < 4; ++i) {
            Ar[i][0].u4 = wa[i * 256];
            Ar[i][1].u4 = wa[i * 256 + 64];
        }
        HB Bop[2][4];
#pragma unroll
        for (int r = 0; r < 4; ++r) {
            const char* sp = xs + (rowbase + r) * TCOLS * PSTRIDE + xlane;
            Bop[0][r].q[0] = *(const unsigned long long*)sp;
            Bop[0][r].q[1] = *(const unsigned long long*)(sp + 8);
        }

        // (2) next-cg stage loads, in flight under the whole cg compute
        uint4 S[6];
        if (cg < 3) {
            const uint4* img = img0 + (size_t)(cg + 1) * img_stride;
#pragma unroll
            for (int k = 0; k < 6; ++k) S[k] = img[goff[k]];
        }

        // (3) 18 K-steps, fully unrolled (ring indices static)
#pragma unroll
        for (int s = 0; s < 18; ++s) {
            const int cp = s & 1, np = cp ^ 1;
            if (s < 17) {                              // prefetch B(s+1)
                const int s1 = s + 1, kp1 = s1 >> 1, kk1 = s1 & 1;
                const int kh1 = kp1 / 3, kw1 = kp1 % 3;
#pragma unroll
                for (int r = 0; r < 4; ++r) {
                    const char* sp = xs
                        + (((rowbase + r + kh1) * TCOLS + kw1) * PSTRIDE + kk1 * 32) + xlane;
                    Bop[np][r].q[0] = *(const unsigned long long*)sp;
                    Bop[np][r].q[1] = *(const unsigned long long*)(sp + 8);
                }
            }
            __builtin_amdgcn_s_setprio(1);
#pragma unroll
            for (int r = 0; r < 4; ++r)
#pragma unroll
                for (int f = 0; f < 2; ++f)
                    acc[f][r] = __builtin_amdgcn_mfma_f32_32x32x16_f16(
                        Ar[s & 3][f].h, Bop[cp][r].h, acc[f][r], 0, 0, 0);
            __builtin_amdgcn_s_setprio(0);
            if (s < 14) {                              // refill ring slot with A(s+4)
                Ar[s & 3][0].u4 = wa[(s + 4) * 256];
                Ar[s & 3][1].u4 = wa[(s + 4) * 256 + 64];
            }
        }

        __syncthreads();                               // xs reads done
        if (cg < 3) {
#pragma unroll
            for (int k = 0; k < 6; ++k) {
                char* dst = xs + loff[k];
                *(unsigned long long*)dst = (unsigned long long)S[k].x | ((unsigned long long)S[k].y << 32);
                *(unsigned long long*)(dst + 8) = (unsigned long long)S[k].z | ((unsigned long long)S[k].w << 32);
            }
            __syncthreads();                           // xs(cg+1) visible
        }
    }

    // epilogue: D col=l31, o = op*64 + 32f + (reg&3)+8*(reg>>2)+4*g2
#pragma unroll
    for (int f = 0; f < 2; ++f)
#pragma unroll
        for (int r = 0; r < 4; ++r) {
            const int orow = row0 + rowbase + r;
#pragma unroll
            for (int reg = 0; reg < 16; ++reg) {
                int o = op * 64 + f * 32 + (reg & 3) + 8 * (reg >> 2) + 4 * g2;
                out[(((size_t)b * NO + o) * NH + orow) * NW + col0 + l31] = acc[f][r][reg];
            }
        }
}

extern "C" void kernel_launch(void* const* d_in, const int* in_sizes, int n_in,
                              void* d_out, int out_size, void* d_ws, size_t ws_size,
                              hipStream_t stream) {
    const float* x = (const float*)d_in[0];
    const float* w = (const float*)d_in[1];

    uint4* xpnt = (uint4*)d_ws;                                  // 35.7 MB padded
    uint4* wqp = (uint4*)((char*)d_ws + (size_t)36 * 1024 * 1024);

    prep_all<<<NB * NH + 72 + 128, 256, 0, stream>>>(x, w, xpnt, wqp);
    ring_conv<<<512, 256, 0, stream>>>(xpnt, wqp, (float*)d_out);
}